// Round 14
// baseline (197.444 us; speedup 1.0000x reference)
//
#include <hip/hip_runtime.h>
#include <hip/hip_bf16.h>
#include <math.h>

// SwitchMoE: B=16,T=4096,D=256,H=512,E=8, top-2 routing.
// R14: quarter-H split, 8 phases, SINGLE barrier per phase with Hs[2]
//      ping-pong (16KB each). Wave finishing G2(p) flows directly into
//      G1(p+1) (different Hs buffer) -> cross-wave G1/G2 overlap replaces
//      the second barrier. Safety: entering G1(p+1) requires passing
//      barrier(p), which implies all waves finished G2(p-1) -> Hs[(p+1)&1]
//      (last read in G2(p-1)) is free.

#define N_TOK 65536
#define D_DIM 256
#define H_DIM 512
#define TILE_R 64
#define GRID_TILES 1088   // >= 1024+64 worst-case pair tiles, multiple of 8

typedef __bf16 bf16x8 __attribute__((ext_vector_type(8)));
typedef float f32x4 __attribute__((ext_vector_type(4)));

static __device__ __forceinline__ ushort f2bf(float f) {
    __hip_bfloat16 h = __float2bfloat16(f);  // RNE
    ushort u;
    __builtin_memcpy(&u, &h, 2);
    return u;
}

// Branch-free GeLU, exact-erf via A&S 7.1.26 3-term (|err|<=2.5e-5).
static __device__ __forceinline__ float gelu(float v) {
    const float a = fabsf(v) * 0.70710678118654752f;
    const float t = __builtin_amdgcn_rcpf(fmaf(a, 0.47047f, 1.0f));
    const float p = t * fmaf(t, fmaf(t, 0.7478556f, -0.0958798f), 0.3480242f);
    const float er = fmaf(-p, __expf(-a * a), 1.0f);   // erf(a), a>=0
    const float s = copysignf(er, v);
    return 0.5f * v * (1.0f + s);
}

// ---------------------------------------------------------------------------
// prep: [0,2048) gating (8 thr/token, coalesced) | [2048,3072) pack W.
// W1p: [e][nb=H/16][kb=D/32][lane=64][j=8]; W2p: [e][nb=D/16][kb=H/32][lane=64][j=8]
// ---------------------------------------------------------------------------
__global__ __launch_bounds__(256) void prep(const float* __restrict__ x,
                                            const float* __restrict__ gate_w,
                                            const float* __restrict__ gate_b,
                                            const float* __restrict__ W1,
                                            const float* __restrict__ W2,
                                            ushort* __restrict__ xb,
                                            ushort* __restrict__ W1p,
                                            ushort* __restrict__ W2p,
                                            int* __restrict__ counts,
                                            int* __restrict__ pid_arr,
                                            float2* __restrict__ pw_arr) {
    __shared__ float gwsT[8 * 260];          // transposed + padded: [e][d], row 260
    __shared__ int lc[64];

    const int bid = blockIdx.x;
    const int tid = threadIdx.x;

    if (bid >= 2048) {                       // ---- pack W ----
        const int pid = bid - 2048;
        const int t = (pid & 511) * 256 + tid;
        const int l = t & 63;
        const int lo = l & 15, hi = l >> 4;
        ushort v[8];
        if (pid < 512) {
            const int kb = (t >> 6) & 7;
            const int nb = (t >> 9) & 31;
            const int e  = t >> 14;
            const int k0 = kb * 32 + hi * 8;
            const int n  = nb * 16 + lo;
            const float* src = W1 + (size_t)e * D_DIM * H_DIM + n;
            #pragma unroll
            for (int j = 0; j < 8; ++j)
                v[j] = f2bf(src[(size_t)(k0 + j) * H_DIM]);
            *(uint4*)(W1p + (size_t)t * 8) = *(const uint4*)v;
        } else {
            const int kb = (t >> 6) & 15;
            const int nb = (t >> 10) & 15;
            const int e  = t >> 14;
            const int k0 = kb * 32 + hi * 8;
            const int n  = nb * 16 + lo;
            const float* src = W2 + (size_t)e * H_DIM * D_DIM + n;
            #pragma unroll
            for (int j = 0; j < 8; ++j)
                v[j] = f2bf(src[(size_t)(k0 + j) * D_DIM]);
            *(uint4*)(W2p + (size_t)t * 8) = *(const uint4*)v;
        }
        return;
    }

    // ---- gating: 32 tokens/block, 8 threads/token, fp64 logits ----
    const size_t t0 = (size_t)bid * 32;
    for (int i = tid; i < 2048; i += 256) {
        const int d = i >> 3, e = i & 7;
        gwsT[e * 260 + d] = gate_w[i];
    }
    if (tid < 64) lc[tid] = 0;
    __syncthreads();

    const int m = tid >> 3, q = tid & 7;               // token m, eighth q
    const float* xrow = x + (t0 + m) * D_DIM;
    ushort* xbrow = xb + (t0 + m) * D_DIM;

    double lg[8] = {0, 0, 0, 0, 0, 0, 0, 0};
    #pragma unroll
    for (int it = 0; it < 8; ++it) {
        const int d0 = it * 32 + q * 4;                // coalesced: q spans 128B
        const float4 v = *(const float4*)(xrow + d0);
        ushort4 bv;
        bv.x = f2bf(v.x); bv.y = f2bf(v.y); bv.z = f2bf(v.z); bv.w = f2bf(v.w);
        *(ushort4*)(xbrow + d0) = bv;
        const float vv[4] = {v.x, v.y, v.z, v.w};
        #pragma unroll
        for (int j = 0; j < 4; ++j) {
            const double xv = (double)vv[j];
            #pragma unroll
            for (int e2 = 0; e2 < 8; ++e2)
                lg[e2] += xv * (double)gwsT[e2 * 260 + d0 + j];
        }
    }
    #pragma unroll
    for (int e2 = 0; e2 < 8; ++e2) {
        lg[e2] += __shfl_xor(lg[e2], 1, 64);
        lg[e2] += __shfl_xor(lg[e2], 2, 64);
        lg[e2] += __shfl_xor(lg[e2], 4, 64);
    }

    if (q == 0) {
        int e0 = 0, e1 = -1;
        #pragma unroll
        for (int e2 = 0; e2 < 8; ++e2) lg[e2] += (double)gate_b[e2];
        double b0 = -1e300, b1v = -1e300;
        #pragma unroll
        for (int e2 = 0; e2 < 8; ++e2)
            if (lg[e2] > b0) { b0 = lg[e2]; e0 = e2; }
        #pragma unroll
        for (int e2 = 0; e2 < 8; ++e2)
            if (e2 != e0 && lg[e2] > b1v) { b1v = lg[e2]; e1 = e2; }
        double s = 0;
        #pragma unroll
        for (int e2 = 0; e2 < 8; ++e2) s += exp(lg[e2] - b0);
        const float p0 = (float)(1.0 / s);
        const float p1 = (float)(exp(b1v - b0) / s);
        const int pid = e0 * 8 + e1;
        atomicAdd(&lc[pid], 1);
        const int tok = (int)t0 + m;
        pid_arr[tok] = pid;
        pw_arr[tok] = make_float2(p0, p1);
    }
    __syncthreads();
    if (tid < 64 && lc[tid]) atomicAdd(&counts[tid], lc[tid]);
}

// ---------------------------------------------------------------------------
// scatter: place tokens into pair-bucketed lists (order within bucket is
// irrelevant; per-token math is independent -> deterministic output).
// ---------------------------------------------------------------------------
__global__ __launch_bounds__(256) void scatter(const int* __restrict__ counts,
                                               const int* __restrict__ pid_arr,
                                               const float2* __restrict__ pw_arr,
                                               int* __restrict__ cursor,
                                               int* __restrict__ tok_list,
                                               float* __restrict__ w0l,
                                               float* __restrict__ w1l) {
    __shared__ int lcnt[64];
    __shared__ int lbase[64];
    const int tid = threadIdx.x;
    const int t = blockIdx.x * 256 + tid;
    if (tid < 64) lcnt[tid] = 0;
    __syncthreads();
    const int pid = pid_arr[t];
    const float2 pw = pw_arr[t];
    const int lpos = atomicAdd(&lcnt[pid], 1);
    __syncthreads();
    if (tid < 64) {
        int s = 0;
        for (int i = 0; i < tid; ++i) s += counts[i];
        const int mine = lcnt[tid];
        lbase[tid] = s + (mine ? atomicAdd(&cursor[tid], mine) : 0);
    }
    __syncthreads();
    const int pos = lbase[pid] + lpos;
    tok_list[pos] = t;
    w0l[pos] = pw.x;
    w1l[pos] = pw.y;
}

// ---------------------------------------------------------------------------
// Pair-tile expert kernel: 64 tokens sharing ordered pair (ea,eb). 8 waves.
// 8 phases (unroll 1) = (expert a|b) x (H quarter 0..3), ONE barrier each:
//   G1: wave w -> W1 col-unit qh*8+w (16 hcols), acc1[4], W1 ring-2/dist-1
//   GeLU*gate -> Hs[p&1] (64 x 128cols, 16KB); W2 k=0,1 preloads; barrier
//   G2: K=128 (4 ks, W2 ring-3/dist-2), acc2[4][2] accumulates
// Next G1 writes the OTHER Hs buffer -> no trailing barrier needed.
// W1/W2 streamed once per 64 tokens. Peak regs ~100 <= 128 -> no spill.
// LDS ~66KB -> 2 blocks/CU.
// ---------------------------------------------------------------------------
__global__ __launch_bounds__(512, 4) void moe_expert(const ushort* __restrict__ xb,
                                                     const ushort* __restrict__ W1p,
                                                     const ushort* __restrict__ W2p,
                                                     const float* __restrict__ b1,
                                                     const float* __restrict__ b2,
                                                     const int* __restrict__ counts,
                                                     const int* __restrict__ tok_list,
                                                     const float* __restrict__ w0l,
                                                     const float* __restrict__ w1l,
                                                     float* __restrict__ out) {
    __shared__ __align__(16) char Xs[TILE_R * 512];       // 32KB swizzled
    __shared__ __align__(16) char Hs[2][TILE_R * 256];    // 2 x 16KB ping-pong
    __shared__ int   toks[TILE_R];
    __shared__ float wgt[2][TILE_R];                      // [0]=w0(a), [1]=w1(b)

    // tile count + bijective XCD chunking
    int n = 0;
    for (int i = 0; i < 64; ++i) n += (counts[i] + 63) >> 6;
    const int qn = n >> 3, rn = n & 7;
    const int xc = blockIdx.x & 7, ix = blockIdx.x >> 3;
    if (ix >= qn + (xc < rn ? 1 : 0)) return;
    const int wg = xc * qn + min(xc, rn) + ix;

    // resolve (pair, row0, nval, token-list base)
    int pid = -1, row0 = 0, nv = 0, gbase = 0;
    int st = 0, sc = 0;
    for (int i = 0; i < 64; ++i) {
        const int c = counts[i];
        const int nt = (c + 63) >> 6;
        if (pid < 0 && wg < st + nt) { pid = i; row0 = (wg - st) << 6; nv = min(TILE_R, c - row0); gbase = sc; }
        st += nt; sc += c;
    }
    const int ea = pid >> 3, eb = pid & 7;
    const int gidx = gbase + row0;

    const int tid = threadIdx.x;
    const int w = tid >> 6, l = tid & 63;
    const int lo = l & 15, hi = l >> 4;

    if (tid < TILE_R) {
        const bool vld = tid < nv;
        const int src = gidx + (vld ? tid : 0);
        toks[tid]   = tok_list[src];
        wgt[0][tid] = vld ? w0l[src] : 0.f;
        wgt[1][tid] = vld ? w1l[src] : 0.f;
    }

    // ---- stage gathered X rows (bf16) into swizzled LDS: 8 thr/row, 64B ----
    {
        const int r = tid >> 3;
        const int tk = tok_list[gidx + min(r, nv - 1)];
        const char* src = (const char*)(xb + (size_t)tk * D_DIM) + (tid & 7) * 64;
        char* dst = Xs + r * 512;
        const int bo = (tid & 7) * 64, sw = (r & 7) << 4;
        #pragma unroll
        for (int c = 0; c < 4; ++c)
            *(uint4*)(dst + ((bo + c * 16) ^ sw)) = *(const uint4*)(src + c * 16);
    }
    __syncthreads();

    f32x4 acc2[4][2];
    #pragma unroll
    for (int mi = 0; mi < 4; ++mi)
        #pragma unroll
        for (int ni = 0; ni < 2; ++ni)
            acc2[mi][ni] = (f32x4){0.f, 0.f, 0.f, 0.f};

    #pragma unroll 1
    for (int p = 0; p < 8; ++p) {
        const int ph = p >> 2, qh = p & 3;          // expert slot, H-quarter
        const int ew = ph ? eb : ea;
        char* HsW = Hs[p & 1];

        // ---- GEMM1: wave w -> col-unit qh*8+w (16 hcols); ring-2/dist-1 ----
        const char* w1b = (const char*)W1p + (size_t)(ew * 32 + qh * 8 + w) * 8192 + (size_t)l * 16;

        f32x4 acc1[4];
        #pragma unroll
        for (int tb = 0; tb < 4; ++tb)
            acc1[tb] = (f32x4){0.f, 0.f, 0.f, 0.f};

        bf16x8 wf[2];
        wf[0] = *(const bf16x8*)(w1b);

        #pragma unroll
        for (int ks = 0; ks < 8; ++ks) {
            const int cb = ks & 1;
            if (ks < 7)
                wf[cb ^ 1] = *(const bf16x8*)(w1b + (ks + 1) * 1024);
            #pragma unroll
            for (int tb = 0; tb < 4; ++tb) {
                const int slot = tb * 16 + lo;
                const bf16x8 xf = *(const bf16x8*)(Xs + slot * 512 +
                                  ((ks * 64 + hi * 16) ^ ((slot & 7) << 4)));
                __builtin_amdgcn_s_setprio(1);
                acc1[tb] = __builtin_amdgcn_mfma_f32_16x16x32_bf16(wf[cb], xf, acc1[tb], 0, 0, 0);
                __builtin_amdgcn_s_setprio(0);
            }
        }

        // ---- bias + GeLU, scale by gate weight -> bf16 Hs[p&1] ----
        {
            const int hcE = (qh * 8 + w) * 16 + hi * 4;    // col in expert H
            const int hb  = (w * 16 + hi * 4) * 2;         // byte col in quarter
            const float4 b1q = *(const float4*)(b1 + ew * H_DIM + hcE);
            #pragma unroll
            for (int tb = 0; tb < 4; ++tb) {
                const int slot = tb * 16 + lo;
                const float wt = wgt[ph][slot];
                ushort4 hv;
                hv.x = f2bf(gelu(acc1[tb][0] + b1q.x) * wt);
                hv.y = f2bf(gelu(acc1[tb][1] + b1q.y) * wt);
                hv.z = f2bf(gelu(acc1[tb][2] + b1q.z) * wt);
                hv.w = f2bf(gelu(acc1[tb][3] + b1q.w) * wt);
                *(ushort4*)(HsW + slot * 256 + (hb ^ ((slot & 7) << 4))) = hv;
            }
        }

        // ---- W2 preloads k=0,1 issued BEFORE the barrier (hide in drain) ----
        const char* w2b = (const char*)W2p + ((size_t)(ew * 16 + w * 2) * 16 + qh * 4) * 1024 + (size_t)l * 16;
        bf16x8 wf2[3][2];
        #pragma unroll
        for (int pp = 0; pp < 2; ++pp) {
            wf2[pp][0] = *(const bf16x8*)(w2b + pp * 1024);
            wf2[pp][1] = *(const bf16x8*)(w2b + 16384 + pp * 1024);
        }
        __syncthreads();   // Hs[p&1] ready (the ONLY barrier this phase)

        // ---- GEMM2: K=128 (4 ks), W2 ring-3 / distance-2 ----
        #pragma unroll
        for (int ks = 0; ks < 4; ++ks) {
            const int cb = ks % 3;
            if (ks < 2) {
                const int lb = (ks + 2) % 3;
                wf2[lb][0] = *(const bf16x8*)(w2b + (ks + 2) * 1024);
                wf2[lb][1] = *(const bf16x8*)(w2b + 16384 + (ks + 2) * 1024);
            }
            #pragma unroll
            for (int mi = 0; mi < 4; ++mi) {
                const int slot = mi * 16 + lo;
                const bf16x8 hf = *(const bf16x8*)(HsW + slot * 256 +
                                  ((ks * 64 + hi * 16) ^ ((slot & 7) << 4)));
                __builtin_amdgcn_s_setprio(1);
                #pragma unroll
                for (int ni = 0; ni < 2; ++ni)
                    acc2[mi][ni] = __builtin_amdgcn_mfma_f32_16x16x32_bf16(hf, wf2[cb][ni], acc2[mi][ni], 0, 0, 0);
                __builtin_amdgcn_s_setprio(0);
            }
        }
        // no trailing barrier: next phase writes Hs[(p+1)&1]
    }

    // ---- epilogue: + w0*b2a + w1*b2b, plain stores (no atomics) ----
    #pragma unroll
    for (int ni = 0; ni < 2; ++ni) {
        const int col = w * 32 + ni * 16 + lo;
        const float b2a = b2[ea * D_DIM + col];
        const float b2b = b2[eb * D_DIM + col];
        #pragma unroll
        for (int mi = 0; mi < 4; ++mi) {
            #pragma unroll
            for (int rg = 0; rg < 4; ++rg) {
                const int r = mi * 16 + hi * 4 + rg;
                if (r < nv) {
                    const float v = acc2[mi][ni][rg] + wgt[0][r] * b2a + wgt[1][r] * b2b;
                    out[(size_t)toks[r] * D_DIM + col] = v;
                }
            }
        }
    }
}

// ---------------------------------------------------------------------------
extern "C" void kernel_launch(void* const* d_in, const int* in_sizes, int n_in,
                              void* d_out, int out_size, void* d_ws, size_t ws_size,
                              hipStream_t stream) {
    const float* x      = (const float*)d_in[0];
    const float* gate_w = (const float*)d_in[1];
    const float* gate_b = (const float*)d_in[2];
    const float* W1     = (const float*)d_in[3];
    const float* b1     = (const float*)d_in[4];
    const float* W2     = (const float*)d_in[5];
    const float* b2     = (const float*)d_in[6];
    float* out = (float*)d_out;

    char* ws = (char*)d_ws;
    ushort* xb      = (ushort*)(ws);                        // 33,554,432 B
    ushort* W1p     = (ushort*)(ws + 33554432);             //  2,097,152 B
    ushort* W2p     = (ushort*)(ws + 35651584);             //  2,097,152 B
    int*    pid_arr = (int*)   (ws + 37748736);             //    262,144 B
    float2* pw_arr  = (float2*)(ws + 38010880);             //    524,288 B
    int*    tok_lst = (int*)   (ws + 38535168);             //    262,144 B
    float*  w0l     = (float*) (ws + 38797312);             //    262,144 B
    float*  w1l     = (float*) (ws + 39059456);             //    262,144 B
    int*    counts  = (int*)   (ws + 39321600);             //        256 B
    int*    cursor  = (int*)   (ws + 39321856);             //        256 B

    hipMemsetAsync(counts, 0, 512, stream);   // counts + cursor

    prep<<<dim3(3072), 256, 0, stream>>>(x, gate_w, gate_b, W1, W2,
                                         xb, W1p, W2p, counts, pid_arr, pw_arr);
    scatter<<<dim3(256), 256, 0, stream>>>(counts, pid_arr, pw_arr, cursor,
                                           tok_lst, w0l, w1l);
    moe_expert<<<dim3(GRID_TILES), 512, 0, stream>>>(xb, W1p, W2p, b1, b2, counts,
                                                     tok_lst, w0l, w1l, out);
}

// Round 15
// 178.929 us; speedup vs baseline: 1.1035x; 1.1035x over previous
//
#include <hip/hip_runtime.h>
#include <hip/hip_bf16.h>
#include <math.h>

// SwitchMoE: B=16,T=4096,D=256,H=512,E=8, top-2 routing.
// R15: moe_expert reverted to R13 verbatim (123.5us local floor; R14's
//      quarter-phase ping-pong regressed: +41% bank conflicts, halved
//      MFMA:ds_read ratio). prep gating rewritten: float4 LDS reads of
//      gwsT (64 b128 instead of 256 scalar b32 per thread) + fp32 expf
//      for softmax magnitudes (selection compares stay fp64).

#define N_TOK 65536
#define D_DIM 256
#define H_DIM 512
#define TILE_R 64
#define GRID_TILES 1088   // >= 1024+64 worst-case pair tiles, multiple of 8

typedef __bf16 bf16x8 __attribute__((ext_vector_type(8)));
typedef float f32x4 __attribute__((ext_vector_type(4)));

static __device__ __forceinline__ ushort f2bf(float f) {
    __hip_bfloat16 h = __float2bfloat16(f);  // RNE
    ushort u;
    __builtin_memcpy(&u, &h, 2);
    return u;
}

// Branch-free GeLU, exact-erf via A&S 7.1.26 3-term (|err|<=2.5e-5).
static __device__ __forceinline__ float gelu(float v) {
    const float a = fabsf(v) * 0.70710678118654752f;
    const float t = __builtin_amdgcn_rcpf(fmaf(a, 0.47047f, 1.0f));
    const float p = t * fmaf(t, fmaf(t, 0.7478556f, -0.0958798f), 0.3480242f);
    const float er = fmaf(-p, __expf(-a * a), 1.0f);   // erf(a), a>=0
    const float s = copysignf(er, v);
    return 0.5f * v * (1.0f + s);
}

// ---------------------------------------------------------------------------
// prep: [0,2048) gating (8 thr/token, coalesced, b128 LDS) | [2048,3072) pack W.
// W1p: [e][nb=H/16][kb=D/32][lane=64][j=8]; W2p: [e][nb=D/16][kb=H/32][lane=64][j=8]
// ---------------------------------------------------------------------------
__global__ __launch_bounds__(256) void prep(const float* __restrict__ x,
                                            const float* __restrict__ gate_w,
                                            const float* __restrict__ gate_b,
                                            const float* __restrict__ W1,
                                            const float* __restrict__ W2,
                                            ushort* __restrict__ xb,
                                            ushort* __restrict__ W1p,
                                            ushort* __restrict__ W2p,
                                            int* __restrict__ counts,
                                            int* __restrict__ pid_arr,
                                            float2* __restrict__ pw_arr) {
    __shared__ __align__(16) float gwsT[8 * 264];   // [e][d], row 264 (16B-aligned)
    __shared__ int lc[64];

    const int bid = blockIdx.x;
    const int tid = threadIdx.x;

    if (bid >= 2048) {                       // ---- pack W ----
        const int pid = bid - 2048;
        const int t = (pid & 511) * 256 + tid;
        const int l = t & 63;
        const int lo = l & 15, hi = l >> 4;
        ushort v[8];
        if (pid < 512) {
            const int kb = (t >> 6) & 7;
            const int nb = (t >> 9) & 31;
            const int e  = t >> 14;
            const int k0 = kb * 32 + hi * 8;
            const int n  = nb * 16 + lo;
            const float* src = W1 + (size_t)e * D_DIM * H_DIM + n;
            #pragma unroll
            for (int j = 0; j < 8; ++j)
                v[j] = f2bf(src[(size_t)(k0 + j) * H_DIM]);
            *(uint4*)(W1p + (size_t)t * 8) = *(const uint4*)v;
        } else {
            const int kb = (t >> 6) & 15;
            const int nb = (t >> 10) & 15;
            const int e  = t >> 14;
            const int k0 = kb * 32 + hi * 8;
            const int n  = nb * 16 + lo;
            const float* src = W2 + (size_t)e * H_DIM * D_DIM + n;
            #pragma unroll
            for (int j = 0; j < 8; ++j)
                v[j] = f2bf(src[(size_t)(k0 + j) * D_DIM]);
            *(uint4*)(W2p + (size_t)t * 8) = *(const uint4*)v;
        }
        return;
    }

    // ---- gating: 32 tokens/block, 8 threads/token, fp64 logits ----
    const size_t t0 = (size_t)bid * 32;
    for (int i = tid; i < 2048; i += 256) {
        const int d = i >> 3, e = i & 7;
        gwsT[e * 264 + d] = gate_w[i];
    }
    if (tid < 64) lc[tid] = 0;
    __syncthreads();

    const int m = tid >> 3, q = tid & 7;               // token m, eighth q
    const float* xrow = x + (t0 + m) * D_DIM;
    ushort* xbrow = xb + (t0 + m) * D_DIM;

    double lg[8] = {0, 0, 0, 0, 0, 0, 0, 0};
    #pragma unroll
    for (int it = 0; it < 8; ++it) {
        const int d0 = it * 32 + q * 4;                // coalesced: q spans 128B
        const float4 v = *(const float4*)(xrow + d0);
        ushort4 bv;
        bv.x = f2bf(v.x); bv.y = f2bf(v.y); bv.z = f2bf(v.z); bv.w = f2bf(v.w);
        *(ushort4*)(xbrow + d0) = bv;
        // one b128 LDS read per expert covers all 4 d-values of this iter
        #pragma unroll
        for (int e2 = 0; e2 < 8; ++e2) {
            const float4 g = *(const float4*)(gwsT + e2 * 264 + d0);
            lg[e2] += (double)v.x * (double)g.x;
            lg[e2] += (double)v.y * (double)g.y;
            lg[e2] += (double)v.z * (double)g.z;
            lg[e2] += (double)v.w * (double)g.w;
        }
    }
    #pragma unroll
    for (int e2 = 0; e2 < 8; ++e2) {
        lg[e2] += __shfl_xor(lg[e2], 1, 64);
        lg[e2] += __shfl_xor(lg[e2], 2, 64);
        lg[e2] += __shfl_xor(lg[e2], 4, 64);
    }

    if (q == 0) {
        int e0 = 0, e1 = -1;
        #pragma unroll
        for (int e2 = 0; e2 < 8; ++e2) lg[e2] += (double)gate_b[e2];
        double b0 = -1e300, b1v = -1e300;
        #pragma unroll
        for (int e2 = 0; e2 < 8; ++e2)
            if (lg[e2] > b0) { b0 = lg[e2]; e0 = e2; }
        #pragma unroll
        for (int e2 = 0; e2 < 8; ++e2)
            if (e2 != e0 && lg[e2] > b1v) { b1v = lg[e2]; e1 = e2; }
        // softmax magnitudes in fp32 (selection already fixed in fp64)
        float s = 0.f;
        #pragma unroll
        for (int e2 = 0; e2 < 8; ++e2) s += __expf((float)(lg[e2] - b0));
        const float p0 = 1.0f / s;
        const float p1 = __expf((float)(b1v - b0)) / s;
        const int pid = e0 * 8 + e1;
        atomicAdd(&lc[pid], 1);
        const int tok = (int)t0 + m;
        pid_arr[tok] = pid;
        pw_arr[tok] = make_float2(p0, p1);
    }
    __syncthreads();
    if (tid < 64 && lc[tid]) atomicAdd(&counts[tid], lc[tid]);
}

// ---------------------------------------------------------------------------
// scatter: place tokens into pair-bucketed lists (order within bucket is
// irrelevant; per-token math is independent -> deterministic output).
// ---------------------------------------------------------------------------
__global__ __launch_bounds__(256) void scatter(const int* __restrict__ counts,
                                               const int* __restrict__ pid_arr,
                                               const float2* __restrict__ pw_arr,
                                               int* __restrict__ cursor,
                                               int* __restrict__ tok_list,
                                               float* __restrict__ w0l,
                                               float* __restrict__ w1l) {
    __shared__ int lcnt[64];
    __shared__ int lbase[64];
    const int tid = threadIdx.x;
    const int t = blockIdx.x * 256 + tid;
    if (tid < 64) lcnt[tid] = 0;
    __syncthreads();
    const int pid = pid_arr[t];
    const float2 pw = pw_arr[t];
    const int lpos = atomicAdd(&lcnt[pid], 1);
    __syncthreads();
    if (tid < 64) {
        int s = 0;
        for (int i = 0; i < tid; ++i) s += counts[i];
        const int mine = lcnt[tid];
        lbase[tid] = s + (mine ? atomicAdd(&cursor[tid], mine) : 0);
    }
    __syncthreads();
    const int pos = lbase[pid] + lpos;
    tok_list[pos] = t;
    w0l[pos] = pw.x;
    w1l[pos] = pw.y;
}

// ---------------------------------------------------------------------------
// Pair-tile expert kernel (R13 form): 64 tokens sharing ordered pair (ea,eb).
// 8 waves. 4 phases (unroll 1) = (expert a|b) x (H col-half 0|1):
//   G1: wave w -> 32 hcols of the half (W1 ring-2/dist-1, phase-local preload)
//   GeLU*gate -> Hs; W2 k=0,1 preloads issued BEFORE the Hs barrier.
//   G2: K=256, W2 ring-3/dist-2, acc2[4][2] accumulates.
// W1/W2 streamed ONCE per 64 tokens. Peak live regs ~95 <= 128 -> no spill.
// LDS ~66KB -> 2 blocks/CU.
// ---------------------------------------------------------------------------
__global__ __launch_bounds__(512, 4) void moe_expert(const ushort* __restrict__ xb,
                                                     const ushort* __restrict__ W1p,
                                                     const ushort* __restrict__ W2p,
                                                     const float* __restrict__ b1,
                                                     const float* __restrict__ b2,
                                                     const int* __restrict__ counts,
                                                     const int* __restrict__ tok_list,
                                                     const float* __restrict__ w0l,
                                                     const float* __restrict__ w1l,
                                                     float* __restrict__ out) {
    __shared__ __align__(16) char Xs[TILE_R * 512];    // 32KB swizzled
    __shared__ __align__(16) char Hs[TILE_R * 512];    // 32KB swizzled, 256 hcols
    __shared__ int   toks[TILE_R];
    __shared__ float wgt[2][TILE_R];                   // [0]=w0(a), [1]=w1(b)

    // tile count + bijective XCD chunking
    int n = 0;
    for (int i = 0; i < 64; ++i) n += (counts[i] + 63) >> 6;
    const int qn = n >> 3, rn = n & 7;
    const int xc = blockIdx.x & 7, ix = blockIdx.x >> 3;
    if (ix >= qn + (xc < rn ? 1 : 0)) return;
    const int wg = xc * qn + min(xc, rn) + ix;

    // resolve (pair, row0, nval, token-list base)
    int pid = -1, row0 = 0, nv = 0, gbase = 0;
    int st = 0, sc = 0;
    for (int i = 0; i < 64; ++i) {
        const int c = counts[i];
        const int nt = (c + 63) >> 6;
        if (pid < 0 && wg < st + nt) { pid = i; row0 = (wg - st) << 6; nv = min(TILE_R, c - row0); gbase = sc; }
        st += nt; sc += c;
    }
    const int ea = pid >> 3, eb = pid & 7;
    const int gidx = gbase + row0;

    const int tid = threadIdx.x;
    const int w = tid >> 6, l = tid & 63;
    const int lo = l & 15, hi = l >> 4;

    if (tid < TILE_R) {
        const bool vld = tid < nv;
        const int src = gidx + (vld ? tid : 0);
        toks[tid]   = tok_list[src];
        wgt[0][tid] = vld ? w0l[src] : 0.f;
        wgt[1][tid] = vld ? w1l[src] : 0.f;
    }

    // ---- stage gathered X rows (bf16) into swizzled LDS: 8 thr/row, 64B ----
    {
        const int r = tid >> 3;
        const int tk = tok_list[gidx + min(r, nv - 1)];
        const char* src = (const char*)(xb + (size_t)tk * D_DIM) + (tid & 7) * 64;
        char* dst = Xs + r * 512;
        const int bo = (tid & 7) * 64, sw = (r & 7) << 4;
        #pragma unroll
        for (int c = 0; c < 4; ++c)
            *(uint4*)(dst + ((bo + c * 16) ^ sw)) = *(const uint4*)(src + c * 16);
    }
    __syncthreads();

    f32x4 acc2[4][2];
    #pragma unroll
    for (int mi = 0; mi < 4; ++mi)
        #pragma unroll
        for (int ni = 0; ni < 2; ++ni)
            acc2[mi][ni] = (f32x4){0.f, 0.f, 0.f, 0.f};

    #pragma unroll 1
    for (int phase = 0; phase < 4; ++phase) {
        const int ph = phase >> 1, ch = phase & 1;
        const int ew = ph ? eb : ea;

        // ---- GEMM1: wave w -> 32 hcols; W1 ring-2 / distance-1 ----
        const char* w1b = (const char*)W1p + (size_t)(ew * 32 + ch * 16 + w * 2) * 8192 + (size_t)l * 16;

        f32x4 acc1[2][4];
        #pragma unroll
        for (int nb = 0; nb < 2; ++nb)
            #pragma unroll
            for (int tb = 0; tb < 4; ++tb)
                acc1[nb][tb] = (f32x4){0.f, 0.f, 0.f, 0.f};

        bf16x8 wf[2][2];
        wf[0][0] = *(const bf16x8*)(w1b);
        wf[0][1] = *(const bf16x8*)(w1b + 8192);

        #pragma unroll
        for (int ks = 0; ks < 8; ++ks) {
            const int cb = ks & 1, nx = cb ^ 1;
            if (ks < 7) {
                wf[nx][0] = *(const bf16x8*)(w1b + (ks + 1) * 1024);
                wf[nx][1] = *(const bf16x8*)(w1b + 8192 + (ks + 1) * 1024);
            }
            #pragma unroll
            for (int tb = 0; tb < 4; ++tb) {
                const int slot = tb * 16 + lo;
                const bf16x8 xf = *(const bf16x8*)(Xs + slot * 512 +
                                  ((ks * 64 + hi * 16) ^ ((slot & 7) << 4)));
                __builtin_amdgcn_s_setprio(1);
                #pragma unroll
                for (int nb = 0; nb < 2; ++nb)
                    acc1[nb][tb] = __builtin_amdgcn_mfma_f32_16x16x32_bf16(wf[cb][nb], xf, acc1[nb][tb], 0, 0, 0);
                __builtin_amdgcn_s_setprio(0);
            }
        }

        // ---- bias + GeLU, scale by gate weight -> bf16 Hs (this half) ----
        #pragma unroll
        for (int nb = 0; nb < 2; ++nb) {
            const int hcE = (ch * 16 + w * 2 + nb) * 16 + hi * 4;   // col in expert H
            const int hcH = (w * 2 + nb) * 16 + hi * 4;             // col in Hs half
            const float4 b1q = *(const float4*)(b1 + ew * H_DIM + hcE);
            #pragma unroll
            for (int tb = 0; tb < 4; ++tb) {
                const int slot = tb * 16 + lo;
                const float wt = wgt[ph][slot];
                ushort4 hv;
                hv.x = f2bf(gelu(acc1[nb][tb][0] + b1q.x) * wt);
                hv.y = f2bf(gelu(acc1[nb][tb][1] + b1q.y) * wt);
                hv.z = f2bf(gelu(acc1[nb][tb][2] + b1q.z) * wt);
                hv.w = f2bf(gelu(acc1[nb][tb][3] + b1q.w) * wt);
                *(ushort4*)(Hs + slot * 512 + ((hcH * 2) ^ ((slot & 7) << 4))) = hv;
            }
        }

        // ---- W2 preloads k=0,1 issued BEFORE the barrier (hide in drain) ----
        const char* w2b = (const char*)W2p + ((size_t)(ew * 16 + w * 2) * 16 + ch * 8) * 1024 + (size_t)l * 16;
        bf16x8 wf2[3][2];
        #pragma unroll
        for (int p = 0; p < 2; ++p) {
            wf2[p][0] = *(const bf16x8*)(w2b + p * 1024);
            wf2[p][1] = *(const bf16x8*)(w2b + 16384 + p * 1024);
        }
        __syncthreads();   // Hs half complete

        // ---- GEMM2: K=256, W2 ring-3 / distance-2 ----
        #pragma unroll
        for (int ks = 0; ks < 8; ++ks) {
            const int cb = ks % 3;
            if (ks < 6) {
                const int lb = (ks + 2) % 3;
                wf2[lb][0] = *(const bf16x8*)(w2b + (ks + 2) * 1024);
                wf2[lb][1] = *(const bf16x8*)(w2b + 16384 + (ks + 2) * 1024);
            }
            #pragma unroll
            for (int mi = 0; mi < 4; ++mi) {
                const int slot = mi * 16 + lo;
                const bf16x8 hf = *(const bf16x8*)(Hs + slot * 512 +
                                  ((ks * 64 + hi * 16) ^ ((slot & 7) << 4)));
                __builtin_amdgcn_s_setprio(1);
                #pragma unroll
                for (int ni = 0; ni < 2; ++ni)
                    acc2[mi][ni] = __builtin_amdgcn_mfma_f32_16x16x32_bf16(hf, wf2[cb][ni], acc2[mi][ni], 0, 0, 0);
                __builtin_amdgcn_s_setprio(0);
            }
        }
        if (phase < 3) __syncthreads();   // Hs free before next half's write
    }

    // ---- epilogue: + w0*b2a + w1*b2b, plain stores (no atomics) ----
    #pragma unroll
    for (int ni = 0; ni < 2; ++ni) {
        const int col = w * 32 + ni * 16 + lo;
        const float b2a = b2[ea * D_DIM + col];
        const float b2b = b2[eb * D_DIM + col];
        #pragma unroll
        for (int mi = 0; mi < 4; ++mi) {
            #pragma unroll
            for (int rg = 0; rg < 4; ++rg) {
                const int r = mi * 16 + hi * 4 + rg;
                if (r < nv) {
                    const float v = acc2[mi][ni][rg] + wgt[0][r] * b2a + wgt[1][r] * b2b;
                    out[(size_t)toks[r] * D_DIM + col] = v;
                }
            }
        }
    }
}

// ---------------------------------------------------------------------------
extern "C" void kernel_launch(void* const* d_in, const int* in_sizes, int n_in,
                              void* d_out, int out_size, void* d_ws, size_t ws_size,
                              hipStream_t stream) {
    const float* x      = (const float*)d_in[0];
    const float* gate_w = (const float*)d_in[1];
    const float* gate_b = (const float*)d_in[2];
    const float* W1     = (const float*)d_in[3];
    const float* b1     = (const float*)d_in[4];
    const float* W2     = (const float*)d_in[5];
    const float* b2     = (const float*)d_in[6];
    float* out = (float*)d_out;

    char* ws = (char*)d_ws;
    ushort* xb      = (ushort*)(ws);                        // 33,554,432 B
    ushort* W1p     = (ushort*)(ws + 33554432);             //  2,097,152 B
    ushort* W2p     = (ushort*)(ws + 35651584);             //  2,097,152 B
    int*    pid_arr = (int*)   (ws + 37748736);             //    262,144 B
    float2* pw_arr  = (float2*)(ws + 38010880);             //    524,288 B
    int*    tok_lst = (int*)   (ws + 38535168);             //    262,144 B
    float*  w0l     = (float*) (ws + 38797312);             //    262,144 B
    float*  w1l     = (float*) (ws + 39059456);             //    262,144 B
    int*    counts  = (int*)   (ws + 39321600);             //        256 B
    int*    cursor  = (int*)   (ws + 39321856);             //        256 B

    hipMemsetAsync(counts, 0, 512, stream);   // counts + cursor

    prep<<<dim3(3072), 256, 0, stream>>>(x, gate_w, gate_b, W1, W2,
                                         xb, W1p, W2p, counts, pid_arr, pw_arr);
    scatter<<<dim3(256), 256, 0, stream>>>(counts, pid_arr, pw_arr, cursor,
                                           tok_lst, w0l, w1l);
    moe_expert<<<dim3(GRID_TILES), 512, 0, stream>>>(xb, W1p, W2p, b1, b2, counts,
                                                     tok_lst, w0l, w1l, out);
}